// Round 6
// baseline (110.333 us; speedup 1.0000x reference)
//
#include <hip/hip_runtime.h>
#include <hip/hip_bf16.h>

typedef _Float16 f16;
typedef f16 f16x4 __attribute__((ext_vector_type(4)));
typedef f16 f16x8 __attribute__((ext_vector_type(8)));
typedef float f32x4 __attribute__((ext_vector_type(4)));

#define DIM   768
#define NP    196
#define BATCH 64
#define MROWS (BATCH * NP)        // 12544
#define NCOLS (3 * DIM)           // 2304
#define GRIDF 14.0f

// ---------------- Kernel 1: f32 -> f16 conversion of [Wq;Wk;Wv] + fused bias array ----------------
#define NW4   (DIM * DIM / 4)     // 147456 float4 per W
#define NB4   (NCOLS / 4)         // 576 float4 of fused bias
#define NWCVT (3 * NW4 + NB4)

__global__ __launch_bounds__(256) void convert_w(
    const float* __restrict__ Wq, const float* __restrict__ Wk, const float* __restrict__ Wv,
    const float* __restrict__ bq, const float* __restrict__ bk, const float* __restrict__ bv,
    f16* __restrict__ W_h, float* __restrict__ bias_all) {
  int i = blockIdx.x * 256 + threadIdx.x;
  if (i >= NWCVT) return;
  if (i < 3 * NW4) {
    const float* src;
    f16* dst;
    int j = i;
    if (j < NW4)          { src = Wq; dst = W_h; }
    else if (j < 2 * NW4) { src = Wk; dst = W_h + DIM * DIM;     j -= NW4; }
    else                  { src = Wv; dst = W_h + 2 * DIM * DIM; j -= 2 * NW4; }
    float4 v = ((const float4*)src)[j];
    f16x4 h;
    h[0] = (f16)v.x; h[1] = (f16)v.y; h[2] = (f16)v.z; h[3] = (f16)v.w;
    ((f16x4*)dst)[j] = h;
  } else {
    int j = i - 3 * NW4;   // 0..575
    float4 v = (j < 192) ? ((const float4*)bq)[j]
             : (j < 384) ? ((const float4*)bk)[j - 192]
                         : ((const float4*)bv)[j - 384];
    ((float4*)bias_all)[j] = v;
  }
}

// ---------------- Kernel 2: qkv = x @ W^T + bias (256x256 8-phase, fused x-cast, coalesced epi) ----
// x: (12544 x 768) f32 rm (A, cast to f16 during reg-staging). W_h: (2304 x 768) f16 rm (B^T).
// BM=BN=256, BK=64, 8 waves (2M x 4N), wave tile 128x64.
// A: reg-staged; A_ISSUE placed TWO PHASES before A_WRITE (T14 issue-early/write-late).
// B: global_load_lds x16. vmcnt ledger (A-loads count too!):
//   at ph4/ph8 outstanding = {B(prev-odd):4 oldest, A(next):8, B(next):4} = 16 -> vmcnt(12)
//   drains exactly the consumed B tile; compiler's pA-use wait at ph1/ph5 drains A's 8.

#define BM 256
#define BN 256
#define BK 64
#define NT    (DIM / BK)   // 12
#define NITER (NT / 2)     // 6

__device__ __forceinline__ void gl_lds16(const f16* g, f16* l) {
  __builtin_amdgcn_global_load_lds(
      (const __attribute__((address_space(1))) void*)g,
      (__attribute__((address_space(3))) void*)l, 16, 0, 0);
}

#define MFMA16(acc_, av, bv) acc_ = __builtin_amdgcn_mfma_f32_16x16x32_f16(av, bv, acc_, 0, 0, 0)
#define BAR     __builtin_amdgcn_s_barrier()
#define LGKM0   asm volatile("s_waitcnt lgkmcnt(0)" ::: "memory")
#define VMCNT12 asm volatile("s_waitcnt vmcnt(12)" ::: "memory")
#define VMCNT0  asm volatile("s_waitcnt vmcnt(0)" ::: "memory")

#define sAoff(buf) ((buf) * (BM * BK))
#define sBoff(buf) (2 * BM * BK + (buf) * (BN * BK))

__global__ __launch_bounds__(512, 2) void gemm_qkv(
    const float* __restrict__ X, const f16* __restrict__ W,
    const float* __restrict__ bias_all, f16* __restrict__ C) {
  __shared__ __align__(16) f16 lds[2 * BM * BK + 2 * BN * BK];  // 131072 B

  const int t    = threadIdx.x;
  const int lane = t & 63;
  const int wid  = t >> 6;
  const int wr   = wid >> 2;       // 0..1  (M)
  const int wc   = wid & 3;        // 0..3  (N)

  // Bijective XCD swizzle (m204) over 441 blocks; logical: n fastest (9 N-blocks)
  const int nwg = 49 * 9, qq = nwg / 8, rr = nwg % 8;
  const int xcd = blockIdx.x & 7, seq = blockIdx.x >> 3;
  const int logical = (xcd < rr ? xcd * (qq + 1) : rr * (qq + 1) + (xcd - rr) * qq) + seq;
  const int bm0 = (logical / 9) * BM;
  const int bn0 = (logical % 9) * BN;

  // Staging coords: thread covers (row = t>>3, slot = t&7); source col pre-swizzled, LDS linear.
  const int srow  = t >> 3;                    // 0..63
  const int sslot = t & 7;
  const int gcol  = 8 * (sslot ^ (srow & 7));  // swizzled source column (elements)
  const int lds_off = srow * BK + sslot * 8;   // linear dest (f16)
  const f16* gBr = W + (size_t)(bn0 + srow) * DIM + gcol;

  float4 pA0, pA1, pA2, pA3, pA4, pA5, pA6, pA7;

#define A_ISSUE(kt) do {                                                      \
    const float* _g0 = X + (size_t)(bm0 + srow) * DIM + (kt) * BK + gcol;     \
    pA0 = *(const float4*)_g0;               pA1 = *(const float4*)(_g0 + 4); \
    pA2 = *(const float4*)(_g0 + 64 * DIM);  pA3 = *(const float4*)(_g0 + 64 * DIM + 4);  \
    pA4 = *(const float4*)(_g0 + 128 * DIM); pA5 = *(const float4*)(_g0 + 128 * DIM + 4); \
    pA6 = *(const float4*)(_g0 + 192 * DIM); pA7 = *(const float4*)(_g0 + 192 * DIM + 4); \
  } while (0)

// NOTE: parameter names must not collide with vector member tokens (.x/.y/.z/.w).
#define CVT8(dst_, lo_, hi_) do {                                  \
    dst_[0]=(f16)lo_.x; dst_[1]=(f16)lo_.y; dst_[2]=(f16)lo_.z; dst_[3]=(f16)lo_.w; \
    dst_[4]=(f16)hi_.x; dst_[5]=(f16)hi_.y; dst_[6]=(f16)hi_.z; dst_[7]=(f16)hi_.w; } while (0)

#define A_WRITE(kt, h) do {                                                   \
    f16x8 _h0, _h1;                                                           \
    if ((h) == 0) { CVT8(_h0, pA0, pA1); CVT8(_h1, pA2, pA3); }               \
    else          { CVT8(_h0, pA4, pA5); CVT8(_h1, pA6, pA7); }               \
    f16* _l = &lds[sAoff((kt) & 1) + (h) * 128 * BK + lds_off];               \
    *(f16x8*)_l = _h0; *(f16x8*)(_l + 64 * BK) = _h1;                         \
  } while (0)

#define STAGE_B(kt, h) do {                                                   \
    const f16* _g = gBr + (size_t)((h) * 128) * DIM + (kt) * BK;              \
    f16* _l = &lds[sBoff((kt) & 1) + (h) * 128 * BK + lds_off];               \
    gl_lds16(_g, _l);                                                         \
    gl_lds16(_g + (size_t)64 * DIM, _l + 64 * BK);                            \
  } while (0)

  // Fragment-read coords
  const int rl = lane & 15;
  const int kg = lane >> 4;        // 0..3
  const int s7 = lane & 7;
  const int slot0 = ((0 * 4 + kg) ^ s7) * 8;   // kh=0 swizzled slot (f16)
  const int slot1 = ((1 * 4 + kg) ^ s7) * 8;   // kh=1
  const int aBase = (wr * 128 + rl) * BK;
  const int bBase = (wc * 64 + rl) * BK;

  f32x4 acc[8][4] = {};
  f16x8 afr[2][2], bfr[4][2];

#define LDB(buf) do {                                                                   \
    _Pragma("unroll") for (int ni = 0; ni < 4; ++ni) {                                  \
      bfr[ni][0] = *(const f16x8*)&lds[sBoff(buf) + bBase + ni * 16 * BK + slot0];      \
      bfr[ni][1] = *(const f16x8*)&lds[sBoff(buf) + bBase + ni * 16 * BK + slot1];      \
    } } while (0)

#define LDA(buf, q_) do {                                                               \
    _Pragma("unroll") for (int mm = 0; mm < 2; ++mm) {                                  \
      afr[mm][0] = *(const f16x8*)&lds[sAoff(buf) + aBase + ((q_) * 2 + mm) * 16 * BK + slot0]; \
      afr[mm][1] = *(const f16x8*)&lds[sAoff(buf) + aBase + ((q_) * 2 + mm) * 16 * BK + slot1]; \
    } } while (0)

  // SWAPPED operand order: mfma(bfr, afr) -> m = lane&15, n = 4*(lane>>4)+reg (contiguous cols/lane)
#define MMA(q_) do {                                                                    \
    __builtin_amdgcn_s_setprio(1);                                                      \
    _Pragma("unroll") for (int ni = 0; ni < 4; ++ni) {                                  \
      MFMA16(acc[(q_) * 2 + 0][ni], bfr[ni][0], afr[0][0]);                             \
      MFMA16(acc[(q_) * 2 + 1][ni], bfr[ni][0], afr[1][0]);                             \
      MFMA16(acc[(q_) * 2 + 0][ni], bfr[ni][1], afr[0][1]);                             \
      MFMA16(acc[(q_) * 2 + 1][ni], bfr[ni][1], afr[1][1]);                             \
    }                                                                                   \
    __builtin_amdgcn_s_setprio(0); } while (0)

  // ---- Prologue: A(0) issue+write (one exposed drain, unavoidable), B(0)+B(1) staged,
  //      A(1) issued here so iter-0 ph1's write has full cover.
  A_ISSUE(0);
  STAGE_B(0, 0); STAGE_B(0, 1);
  A_WRITE(0, 0); A_WRITE(0, 1);    // compiler drains A(0)'s 8 loads (oldest)
  A_ISSUE(1);
  STAGE_B(1, 0); STAGE_B(1, 1);
  VMCNT12;      // outstanding {B(0):4 oldest, A(1):8, B(1):4} -> drain B(0)
  LGKM0;        // A(0) ds_writes drained
  BAR;

  for (int i = 0; i < NITER; ++i) {
    const int t1 = 2 * i + 1;
    const bool more = (i + 1 < NITER);
    // ph1: consume buf0; write A(t1) (issued 2 phases ago, prev ph7 / prologue)
    LDB(0); LDA(0, 0); A_WRITE(t1, 0);
    BAR; LGKM0; MMA(0); BAR;
    // ph2
    LDA(0, 1); A_WRITE(t1, 1);
    BAR; LGKM0; MMA(1); BAR;
    // ph3: issue A(t1+1) EARLY (consumed ph5/ph6), stage B(t1+1) half0
    LDA(0, 2); if (more) { A_ISSUE(t1 + 1); STAGE_B(t1 + 1, 0); }
    BAR; LGKM0; MMA(2); BAR;
    // ph4: vmcnt(12) drains B(t1) (oldest 4) before ph5 consumes buf1
    LDA(0, 3); if (more) STAGE_B(t1 + 1, 1);
    BAR; LGKM0; MMA(3);
    if (more) { VMCNT12; } else { VMCNT0; }
    BAR;
    // ph5: consume buf1; write A(t1+1) (issued ph3)
    LDB(1); LDA(1, 0); if (more) A_WRITE(t1 + 1, 0);
    BAR; LGKM0; MMA(0); BAR;
    // ph6
    LDA(1, 1); if (more) A_WRITE(t1 + 1, 1);
    BAR; LGKM0; MMA(1); BAR;
    // ph7: issue A(t1+2) EARLY (consumed next-iter ph1/ph2), stage B(t1+2) half0
    LDA(1, 2); if (more) { A_ISSUE(t1 + 2); STAGE_B(t1 + 2, 0); }
    BAR; LGKM0; MMA(2); BAR;
    // ph8: vmcnt(12) drains B(t1+1) before next-iter ph1 consumes buf0
    LDA(1, 3); if (more) STAGE_B(t1 + 2, 1);
    BAR; LGKM0; MMA(3);
    if (more) { VMCNT12; } else { VMCNT0; }
    BAR;
  }

  // ---- Epilogue: acc -> swizzled LDS C-tile (f16, bias fused) -> coalesced global stores
  {
    const int mloc0 = wr * 128 + rl;
    const int nq0   = wc * 64 + 4 * kg;
#pragma unroll
    for (int ni = 0; ni < 4; ++ni) {
      const int nloc = nq0 + ni * 16;
      const float4 b4 = *(const float4*)&bias_all[bn0 + nloc];
#pragma unroll
      for (int mi = 0; mi < 8; ++mi) {
        const int m = mloc0 + mi * 16;
        f16x4 h;
        h[0] = (f16)(acc[mi][ni][0] + b4.x);
        h[1] = (f16)(acc[mi][ni][1] + b4.y);
        h[2] = (f16)(acc[mi][ni][2] + b4.z);
        h[3] = (f16)(acc[mi][ni][3] + b4.w);
        *(f16x4*)&lds[m * 256 + (nloc ^ ((m & 7) << 3))] = h;
      }
    }
    LGKM0; BAR;
    const int rrow = t >> 5;       // 0..15
    const int rchk = t & 31;       // 0..31, 8 f16 each
#pragma unroll
    for (int p = 0; p < 16; ++p) {
      const int row = p * 16 + rrow;
      f16x8 vdat = *(const f16x8*)&lds[row * 256 + ((rchk * 8) ^ ((row & 7) << 3))];
      *(f16x8*)&C[(size_t)(bm0 + row) * NCOLS + bn0 + rchk * 8] = vdat;
    }
  }
}

// ---------------- Kernel 3: gather + 4-way per-feature softmax + weighted sum ----------------
// XCD-chunked block swizzle: 3136 blocks = 8 * 392; each XCD gets 392 consecutive blocks.
__global__ __launch_bounds__(256) void attend(
    const f16* __restrict__ qkv,
    const int* __restrict__ img_ids, const float* __restrict__ eps,
    const float* __restrict__ avgs, const float* __restrict__ stds,
    float* __restrict__ out) {
  const int lane = threadIdx.x & 63;
  const int wid  = threadIdx.x >> 6;
  const int logical = (blockIdx.x & 7) * 392 + (blockIdx.x >> 3);
  const int gw = logical * 4 + wid;          // (b*196 + s)
  const int b = gw / NP;
  const int s = gw - b * NP;

  const int img = img_ids[b];
  const float ex = eps[(b * 2 + 0) * NP + s];
  const float ey = eps[(b * 2 + 1) * NP + s];
  const float mux = avgs[(img * 2 + 0) * NP + s];
  const float muy = avgs[(img * 2 + 1) * NP + s];
  const float sdx = stds[(img * 2 + 0) * NP + s];
  const float sdy = stds[(img * 2 + 1) * NP + s];

  const float kx = fmaf(sdx, ex, mux);
  const float ky = fmaf(sdy, ey, muy);
  const float kx1 = ceilf(kx), kx2 = floorf(kx);
  const float ky1 = ceilf(ky), ky2 = floorf(ky);

  int idx[4];
  idx[0] = (int)fminf(fmaxf(GRIDF * ky1 + kx1, 0.0f), 195.0f);
  idx[1] = (int)fminf(fmaxf(GRIDF * ky1 + kx2, 0.0f), 195.0f);
  idx[2] = (int)fminf(fmaxf(GRIDF * ky2 + kx1, 0.0f), 195.0f);
  idx[3] = (int)fminf(fmaxf(GRIDF * ky2 + kx2, 0.0f), 195.0f);

  const f16* qrow = qkv + (size_t)gw * NCOLS;
  const f16* base = qkv + (size_t)(b * NP) * NCOLS;
  const f16* k0p = base + (size_t)idx[0] * NCOLS + DIM;
  const f16* k1p = base + (size_t)idx[1] * NCOLS + DIM;
  const f16* k2p = base + (size_t)idx[2] * NCOLS + DIM;
  const f16* k3p = base + (size_t)idx[3] * NCOLS + DIM;
  const f16* v0p = k0p + DIM;
  const f16* v1p = k1p + DIM;
  const f16* v2p = k2p + DIM;
  const f16* v3p = k3p + DIM;
  float* orow = out + (size_t)gw * DIM;

#pragma unroll
  for (int seg = 0; seg < 3; ++seg) {
    const int e0 = seg * 256 + lane * 4;
    f16x4 qv  = *(const f16x4*)(qrow + e0);
    f16x4 kv0 = *(const f16x4*)(k0p + e0);
    f16x4 kv1 = *(const f16x4*)(k1p + e0);
    f16x4 kv2 = *(const f16x4*)(k2p + e0);
    f16x4 kv3 = *(const f16x4*)(k3p + e0);
    f16x4 vv0 = *(const f16x4*)(v0p + e0);
    f16x4 vv1 = *(const f16x4*)(v1p + e0);
    f16x4 vv2 = *(const f16x4*)(v2p + e0);
    f16x4 vv3 = *(const f16x4*)(v3p + e0);
    float4 o;
    float* op = &o.x;
#pragma unroll
    for (int c = 0; c < 4; ++c) {
      const float q = (float)qv[c];
      const float s0 = q * (float)kv0[c];
      const float s1 = q * (float)kv1[c];
      const float s2 = q * (float)kv2[c];
      const float s3 = q * (float)kv3[c];
      const float mx = fmaxf(fmaxf(s0, s1), fmaxf(s2, s3));
      const float w0 = __expf(s0 - mx);
      const float w1 = __expf(s1 - mx);
      const float w2 = __expf(s2 - mx);
      const float w3 = __expf(s3 - mx);
      const float den = w0 + w1 + w2 + w3;
      const float num = w0 * (float)vv0[c] + w1 * (float)vv1[c] +
                        w2 * (float)vv2[c] + w3 * (float)vv3[c];
      op[c] = num / den;
    }
    *(float4*)(orow + e0) = o;
  }
}

// ---------------- Launch ----------------
extern "C" void kernel_launch(void* const* d_in, const int* in_sizes, int n_in,
                              void* d_out, int out_size, void* d_ws, size_t ws_size,
                              hipStream_t stream) {
  const float* x       = (const float*)d_in[0];
  const int*   img_ids = (const int*)d_in[2];
  const float* eps     = (const float*)d_in[3];
  const float* Wq      = (const float*)d_in[4];
  const float* bq      = (const float*)d_in[5];
  const float* Wk      = (const float*)d_in[6];
  const float* bk      = (const float*)d_in[7];
  const float* Wv      = (const float*)d_in[8];
  const float* bv      = (const float*)d_in[9];
  const float* avgs    = (const float*)d_in[10];
  const float* stds    = (const float*)d_in[11];
  float* out = (float*)d_out;

  char* ws = (char*)d_ws;
  const size_t WH_BYTES = (size_t)NCOLS * DIM * 2;   // 3,538,944
  const size_t BI_BYTES = (size_t)NCOLS * 4;         // 9,216
  f16*   W_h      = (f16*)ws;
  float* bias_all = (float*)(ws + WH_BYTES);
  f16*   qkv      = (f16*)(ws + WH_BYTES + BI_BYTES);

  {
    int grid = (NWCVT + 255) / 256;
    convert_w<<<grid, 256, 0, stream>>>(Wq, Wk, Wv, bq, bk, bv, W_h, bias_all);
  }
  {
    gemm_qkv<<<441, 512, 0, stream>>>(x, W_h, bias_all, qkv);
  }
  {
    int grid = MROWS / 4;
    attend<<<grid, 256, 0, stream>>>(qkv, img_ids, eps, avgs, stds, out);
  }
}

// Round 7
// 83.635 us; speedup vs baseline: 1.3192x; 1.3192x over previous
//
#include <hip/hip_runtime.h>
#include <hip/hip_bf16.h>

typedef _Float16 f16;
typedef f16 f16x4 __attribute__((ext_vector_type(4)));
typedef f16 f16x8 __attribute__((ext_vector_type(8)));
typedef float f32x4 __attribute__((ext_vector_type(4)));

#define DIM   768
#define NP    196
#define BATCH 64
#define MROWS (BATCH * NP)        // 12544
#define NCOLS (3 * DIM)           // 2304
#define GRIDF 14.0f

// ---------------- Kernel 1: f32 -> f16 conversion of x and [Wq;Wk;Wv] + bias array ----------------
#define NX4   (MROWS * DIM / 4)   // 2,408,448
#define NW4   (DIM * DIM / 4)     // 147,456 per W
#define NB4   (NCOLS / 4)         // 576
#define NCVTA (NX4 + 3 * NW4 + NB4)

__global__ __launch_bounds__(256) void convert_inputs(
    const float* __restrict__ x,
    const float* __restrict__ Wq, const float* __restrict__ Wk, const float* __restrict__ Wv,
    const float* __restrict__ bq, const float* __restrict__ bk, const float* __restrict__ bv,
    f16* __restrict__ x_h, f16* __restrict__ W_h, float* __restrict__ bias_all) {
  int i = blockIdx.x * 256 + threadIdx.x;
  if (i >= NCVTA) return;
  if (i < NX4 + 3 * NW4) {
    const float* src;
    f16* dst;
    int j;
    if (i < NX4) { src = x; dst = x_h; j = i; }
    else {
      j = i - NX4;
      if (j < NW4)          { src = Wq; dst = W_h; }
      else if (j < 2 * NW4) { src = Wk; dst = W_h + DIM * DIM;     j -= NW4; }
      else                  { src = Wv; dst = W_h + 2 * DIM * DIM; j -= 2 * NW4; }
    }
    float4 v = ((const float4*)src)[j];
    f16x4 h;
    h[0] = (f16)v.x; h[1] = (f16)v.y; h[2] = (f16)v.z; h[3] = (f16)v.w;
    ((f16x4*)dst)[j] = h;
  } else {
    int j = i - (NX4 + 3 * NW4);   // 0..575
    float4 v = (j < 192) ? ((const float4*)bq)[j]
             : (j < 384) ? ((const float4*)bk)[j - 192]
                         : ((const float4*)bv)[j - 384];
    ((float4*)bias_all)[j] = v;
  }
}

// ---------------- Kernel 2: qkv = x_h @ W_h^T + bias (256x256 8-phase, r3 main loop) ----------------
// A: (12544 x 768) f16 rm. W: (2304 x 768) f16 rm (B^T). BM=BN=256, BK=64,
// 8 waves (2M x 4N), wave tile 128x64. Both operands via global_load_lds (m151:
// gload_lds beats reg-staging at linear-LDS tiles). XOR-slot swizzle via
// pre-swizzled global source + swizzled ds_read. Counted vmcnt(4) at ph4/ph8.
// Epilogue: swapped-operand acc -> swizzled LDS C-tile -> coalesced 16B stores.

#define BM 256
#define BN 256
#define BK 64
#define NT    (DIM / BK)   // 12
#define NITER (NT / 2)     // 6

__device__ __forceinline__ void gl_lds16(const f16* g, f16* l) {
  __builtin_amdgcn_global_load_lds(
      (const __attribute__((address_space(1))) void*)g,
      (__attribute__((address_space(3))) void*)l, 16, 0, 0);
}

#define MFMA16(acc_, av, bv) acc_ = __builtin_amdgcn_mfma_f32_16x16x32_f16(av, bv, acc_, 0, 0, 0)
#define BAR    __builtin_amdgcn_s_barrier()
#define LGKM0  asm volatile("s_waitcnt lgkmcnt(0)" ::: "memory")
#define VMCNT4 asm volatile("s_waitcnt vmcnt(4)" ::: "memory")
#define VMCNT0 asm volatile("s_waitcnt vmcnt(0)" ::: "memory")

#define sAoff(buf) ((buf) * (BM * BK))
#define sBoff(buf) (2 * BM * BK + (buf) * (BN * BK))

__global__ __launch_bounds__(512, 2) void gemm_qkv(
    const f16* __restrict__ A, const f16* __restrict__ W,
    const float* __restrict__ bias_all, f16* __restrict__ C) {
  __shared__ __align__(16) f16 lds[2 * BM * BK + 2 * BN * BK];  // 131072 B

  const int t    = threadIdx.x;
  const int lane = t & 63;
  const int wid  = t >> 6;
  const int wr   = wid >> 2;       // 0..1  (M)
  const int wc   = wid & 3;        // 0..3  (N)

  // Bijective XCD swizzle (m204) over 441 blocks; logical: n fastest (9 N-blocks)
  const int nwg = 49 * 9, qq = nwg / 8, rr = nwg % 8;
  const int xcd = blockIdx.x & 7, seq = blockIdx.x >> 3;
  const int logical = (xcd < rr ? xcd * (qq + 1) : rr * (qq + 1) + (xcd - rr) * qq) + seq;
  const int bm0 = (logical / 9) * BM;
  const int bn0 = (logical % 9) * BN;

  // Staging coords: thread covers (row = t>>3, slot = t&7); source col pre-swizzled, LDS linear.
  const int srow  = t >> 3;                    // 0..63
  const int sslot = t & 7;
  const int gcol  = 8 * (sslot ^ (srow & 7));  // swizzled source column (elements)
  const int lds_off = srow * BK + sslot * 8;   // linear dest (f16)
  const f16* gAr = A + (size_t)(bm0 + srow) * DIM + gcol;
  const f16* gBr = W + (size_t)(bn0 + srow) * DIM + gcol;

#define STAGE_A(kt, h) do {                                          \
    const f16* _g = gAr + (size_t)((h) * 128) * DIM + (kt) * BK;     \
    f16* _l = &lds[sAoff((kt) & 1) + (h) * 128 * BK + lds_off];      \
    gl_lds16(_g, _l);                                                \
    gl_lds16(_g + (size_t)64 * DIM, _l + 64 * BK);                   \
  } while (0)

#define STAGE_B(kt, h) do {                                          \
    const f16* _g = gBr + (size_t)((h) * 128) * DIM + (kt) * BK;     \
    f16* _l = &lds[sBoff((kt) & 1) + (h) * 128 * BK + lds_off];      \
    gl_lds16(_g, _l);                                                \
    gl_lds16(_g + (size_t)64 * DIM, _l + 64 * BK);                   \
  } while (0)

  // Fragment-read coords
  const int rl = lane & 15;
  const int kg = lane >> 4;        // 0..3
  const int s7 = lane & 7;
  const int slot0 = ((0 * 4 + kg) ^ s7) * 8;   // kh=0 swizzled slot (f16)
  const int slot1 = ((1 * 4 + kg) ^ s7) * 8;   // kh=1
  const int aBase = (wr * 128 + rl) * BK;
  const int bBase = (wc * 64 + rl) * BK;

  f32x4 acc[8][4] = {};
  f16x8 afr[2][2], bfr[4][2];

#define LDB(buf) do {                                                                   \
    _Pragma("unroll") for (int ni = 0; ni < 4; ++ni) {                                  \
      bfr[ni][0] = *(const f16x8*)&lds[sBoff(buf) + bBase + ni * 16 * BK + slot0];      \
      bfr[ni][1] = *(const f16x8*)&lds[sBoff(buf) + bBase + ni * 16 * BK + slot1];      \
    } } while (0)

#define LDA(buf, q_) do {                                                               \
    _Pragma("unroll") for (int mm = 0; mm < 2; ++mm) {                                  \
      afr[mm][0] = *(const f16x8*)&lds[sAoff(buf) + aBase + ((q_) * 2 + mm) * 16 * BK + slot0]; \
      afr[mm][1] = *(const f16x8*)&lds[sAoff(buf) + aBase + ((q_) * 2 + mm) * 16 * BK + slot1]; \
    } } while (0)

  // SWAPPED operand order: mfma(bfr, afr) -> m = lane&15, n = 4*(lane>>4)+reg (contiguous cols/lane)
#define MMA(q_) do {                                                                    \
    __builtin_amdgcn_s_setprio(1);                                                      \
    _Pragma("unroll") for (int ni = 0; ni < 4; ++ni) {                                  \
      MFMA16(acc[(q_) * 2 + 0][ni], bfr[ni][0], afr[0][0]);                             \
      MFMA16(acc[(q_) * 2 + 1][ni], bfr[ni][0], afr[1][0]);                             \
      MFMA16(acc[(q_) * 2 + 0][ni], bfr[ni][1], afr[0][1]);                             \
      MFMA16(acc[(q_) * 2 + 1][ni], bfr[ni][1], afr[1][1]);                             \
    }                                                                                   \
    __builtin_amdgcn_s_setprio(0); } while (0)

  // ---- Prologue: tile0 full + tile1 B; tile0 landed via vmcnt(4), tile1.B in flight
  STAGE_A(0, 0); STAGE_A(0, 1); STAGE_B(0, 0); STAGE_B(0, 1);
  STAGE_B(1, 0); STAGE_B(1, 1);
  VMCNT4;
  BAR;

  for (int i = 0; i < NITER; ++i) {
    const int t1 = 2 * i + 1;
    const bool more = (i + 1 < NITER);
    // ph1: consume buf0 {B full + A q0}; stage buf1.A-lo <- tile t1
    LDB(0); LDA(0, 0); STAGE_A(t1, 0);
    BAR; LGKM0; MMA(0); BAR;
    // ph2
    LDA(0, 1); STAGE_A(t1, 1);
    BAR; LGKM0; MMA(1); BAR;
    // ph3
    LDA(0, 2); if (more) STAGE_B(t1 + 1, 0);
    BAR; LGKM0; MMA(2); BAR;
    // ph4: vmcnt(4) drains A(t1)+B(t1), leaves B(t1+1) in flight
    LDA(0, 3); if (more) STAGE_B(t1 + 1, 1);
    BAR; LGKM0; MMA(3);
    if (more) { VMCNT4; } else { VMCNT0; }
    BAR;
    // ph5: consume buf1 {B full + A q0}; stage buf0.A-lo <- tile t1+1
    LDB(1); LDA(1, 0); if (more) STAGE_A(t1 + 1, 0);
    BAR; LGKM0; MMA(0); BAR;
    // ph6
    LDA(1, 1); if (more) STAGE_A(t1 + 1, 1);
    BAR; LGKM0; MMA(1); BAR;
    // ph7
    LDA(1, 2); if (more) STAGE_B(t1 + 2, 0);
    BAR; LGKM0; MMA(2); BAR;
    // ph8: vmcnt(4) drains tile t1+1 fully, leaves B(t1+2)
    LDA(1, 3); if (more) STAGE_B(t1 + 2, 1);
    BAR; LGKM0; MMA(3); VMCNT4; BAR;
  }

  // ---- Epilogue: acc -> swizzled LDS C-tile (f16, bias fused) -> coalesced global stores
  // Swapped layout: m = bm0 + wr*128 + mi*16 + rl ; n = bn0 + wc*64 + ni*16 + 4*kg + reg
  {
    const int mloc0 = wr * 128 + rl;
    const int nq0   = wc * 64 + 4 * kg;
#pragma unroll
    for (int ni = 0; ni < 4; ++ni) {
      const int nloc = nq0 + ni * 16;
      const float4 b4 = *(const float4*)&bias_all[bn0 + nloc];
#pragma unroll
      for (int mi = 0; mi < 8; ++mi) {
        const int m = mloc0 + mi * 16;
        f16x4 h;
        h[0] = (f16)(acc[mi][ni][0] + b4.x);
        h[1] = (f16)(acc[mi][ni][1] + b4.y);
        h[2] = (f16)(acc[mi][ni][2] + b4.z);
        h[3] = (f16)(acc[mi][ni][3] + b4.w);
        *(f16x4*)&lds[m * 256 + (nloc ^ ((m & 7) << 3))] = h;
      }
    }
    LGKM0; BAR;
    const int rrow = t >> 5;       // 0..15
    const int rchk = t & 31;       // 0..31, 8 f16 each
#pragma unroll
    for (int p = 0; p < 16; ++p) {
      const int row = p * 16 + rrow;
      f16x8 vdat = *(const f16x8*)&lds[row * 256 + ((rchk * 8) ^ ((row & 7) << 3))];
      *(f16x8*)&C[(size_t)(bm0 + row) * NCOLS + bn0 + rchk * 8] = vdat;
    }
  }
}

// ---------------- Kernel 3: gather + 4-way per-feature softmax + weighted sum ----------------
// XCD-chunked block swizzle: 3136 blocks = 8 * 392; each XCD gets 392 consecutive blocks.
__global__ __launch_bounds__(256) void attend(
    const f16* __restrict__ qkv,
    const int* __restrict__ img_ids, const float* __restrict__ eps,
    const float* __restrict__ avgs, const float* __restrict__ stds,
    float* __restrict__ out) {
  const int lane = threadIdx.x & 63;
  const int wid  = threadIdx.x >> 6;
  const int logical = (blockIdx.x & 7) * 392 + (blockIdx.x >> 3);
  const int gw = logical * 4 + wid;          // (b*196 + s)
  const int b = gw / NP;
  const int s = gw - b * NP;

  const int img = img_ids[b];
  const float ex = eps[(b * 2 + 0) * NP + s];
  const float ey = eps[(b * 2 + 1) * NP + s];
  const float mux = avgs[(img * 2 + 0) * NP + s];
  const float muy = avgs[(img * 2 + 1) * NP + s];
  const float sdx = stds[(img * 2 + 0) * NP + s];
  const float sdy = stds[(img * 2 + 1) * NP + s];

  const float kx = fmaf(sdx, ex, mux);
  const float ky = fmaf(sdy, ey, muy);
  const float kx1 = ceilf(kx), kx2 = floorf(kx);
  const float ky1 = ceilf(ky), ky2 = floorf(ky);

  int idx[4];
  idx[0] = (int)fminf(fmaxf(GRIDF * ky1 + kx1, 0.0f), 195.0f);
  idx[1] = (int)fminf(fmaxf(GRIDF * ky1 + kx2, 0.0f), 195.0f);
  idx[2] = (int)fminf(fmaxf(GRIDF * ky2 + kx1, 0.0f), 195.0f);
  idx[3] = (int)fminf(fmaxf(GRIDF * ky2 + kx2, 0.0f), 195.0f);

  const f16* qrow = qkv + (size_t)gw * NCOLS;
  const f16* base = qkv + (size_t)(b * NP) * NCOLS;
  const f16* k0p = base + (size_t)idx[0] * NCOLS + DIM;
  const f16* k1p = base + (size_t)idx[1] * NCOLS + DIM;
  const f16* k2p = base + (size_t)idx[2] * NCOLS + DIM;
  const f16* k3p = base + (size_t)idx[3] * NCOLS + DIM;
  const f16* v0p = k0p + DIM;
  const f16* v1p = k1p + DIM;
  const f16* v2p = k2p + DIM;
  const f16* v3p = k3p + DIM;
  float* orow = out + (size_t)gw * DIM;

#pragma unroll
  for (int seg = 0; seg < 3; ++seg) {
    const int e0 = seg * 256 + lane * 4;
    f16x4 qv  = *(const f16x4*)(qrow + e0);
    f16x4 kv0 = *(const f16x4*)(k0p + e0);
    f16x4 kv1 = *(const f16x4*)(k1p + e0);
    f16x4 kv2 = *(const f16x4*)(k2p + e0);
    f16x4 kv3 = *(const f16x4*)(k3p + e0);
    f16x4 vv0 = *(const f16x4*)(v0p + e0);
    f16x4 vv1 = *(const f16x4*)(v1p + e0);
    f16x4 vv2 = *(const f16x4*)(v2p + e0);
    f16x4 vv3 = *(const f16x4*)(v3p + e0);
    float4 o;
    float* op = &o.x;
#pragma unroll
    for (int c = 0; c < 4; ++c) {
      const float q = (float)qv[c];
      const float s0 = q * (float)kv0[c];
      const float s1 = q * (float)kv1[c];
      const float s2 = q * (float)kv2[c];
      const float s3 = q * (float)kv3[c];
      const float mx = fmaxf(fmaxf(s0, s1), fmaxf(s2, s3));
      const float w0 = __expf(s0 - mx);
      const float w1 = __expf(s1 - mx);
      const float w2 = __expf(s2 - mx);
      const float w3 = __expf(s3 - mx);
      const float den = w0 + w1 + w2 + w3;
      const float num = w0 * (float)vv0[c] + w1 * (float)vv1[c] +
                        w2 * (float)vv2[c] + w3 * (float)vv3[c];
      op[c] = num / den;
    }
    *(float4*)(orow + e0) = o;
  }
}

// ---------------- Launch ----------------
extern "C" void kernel_launch(void* const* d_in, const int* in_sizes, int n_in,
                              void* d_out, int out_size, void* d_ws, size_t ws_size,
                              hipStream_t stream) {
  const float* x       = (const float*)d_in[0];
  const int*   img_ids = (const int*)d_in[2];
  const float* eps     = (const float*)d_in[3];
  const float* Wq      = (const float*)d_in[4];
  const float* bq      = (const float*)d_in[5];
  const float* Wk      = (const float*)d_in[6];
  const float* bk      = (const float*)d_in[7];
  const float* Wv      = (const float*)d_in[8];
  const float* bv      = (const float*)d_in[9];
  const float* avgs    = (const float*)d_in[10];
  const float* stds    = (const float*)d_in[11];
  float* out = (float*)d_out;

  char* ws = (char*)d_ws;
  const size_t XH_BYTES = (size_t)MROWS * DIM * 2;   // 19,267,584
  const size_t WH_BYTES = (size_t)NCOLS * DIM * 2;   //  3,538,944
  const size_t BI_BYTES = (size_t)NCOLS * 4;         //      9,216
  f16*   x_h      = (f16*)ws;
  f16*   W_h      = (f16*)(ws + XH_BYTES);
  float* bias_all = (float*)(ws + XH_BYTES + WH_BYTES);
  f16*   qkv      = (f16*)(ws + XH_BYTES + WH_BYTES + BI_BYTES);

  {
    int grid = (NCVTA + 255) / 256;
    convert_inputs<<<grid, 256, 0, stream>>>(x, Wq, Wk, Wv, bq, bk, bv, x_h, W_h, bias_all);
  }
  {
    gemm_qkv<<<441, 512, 0, stream>>>(x_h, W_h, bias_all, qkv);
  }
  {
    int grid = MROWS / 4;
    attend<<<grid, 256, 0, stream>>>(qkv, img_ids, eps, avgs, stds, out);
  }
}